// Round 7
// baseline (1045.985 us; speedup 1.0000x reference)
//
#include <hip/hip_runtime.h>
#include <hip/hip_fp16.h>

#define H_A   2048
#define H_HP  4096
#define DEPTH 12

struct Half8 { __half2 a, b, c, d; };   // 16 B
struct Half4 { __half2 a, b; };         // 8 B

__device__ __forceinline__ float fsig_(float x) { return 1.0f / (1.0f + __expf(-x)); }
__device__ __forceinline__ float ftanh_(float x) {
    return 1.0f - 2.0f / (__expf(2.0f * x) + 1.0f);
}
__device__ __forceinline__ float dot4_(float4 a, float4 b) {
    return a.x * b.x + a.y * b.y + a.z * b.z + a.w * b.w;
}
__device__ __forceinline__ float dot8h_(Half8 w, float4 x0, float4 x1) {
    float2 wa = __half22float2(w.a), wb = __half22float2(w.b);
    float2 wc = __half22float2(w.c), wd = __half22float2(w.d);
    return wa.x * x0.x + wa.y * x0.y + wb.x * x0.z + wb.y * x0.w +
           wc.x * x1.x + wc.y * x1.y + wd.x * x1.z + wd.y * x1.w;
}
__device__ __forceinline__ Half4 cvt4_(float4 a) {
    Half4 h;
    h.a = __floats2half2_rn(a.x, a.y);
    h.b = __floats2half2_rn(a.z, a.w);
    return h;
}
__device__ __forceinline__ Half8 cvt8_(float4 a, float4 b) {
    Half8 h;
    h.a = __floats2half2_rn(a.x, a.y);
    h.b = __floats2half2_rn(a.z, a.w);
    h.c = __floats2half2_rn(b.x, b.y);
    h.d = __floats2half2_rn(b.z, b.w);
    return h;
}
__device__ __forceinline__ float waveReduceSum(float v) {
#pragma unroll
    for (int off = 32; off > 0; off >>= 1) v += __shfl_xor(v, off, 64);
    return v;
}
__device__ __forceinline__ void waveReduce4(float& a0, float& a1, float& a2, float& a3) {
#pragma unroll
    for (int off = 32; off > 0; off >>= 1) {
        a0 += __shfl_xor(a0, off, 64);
        a1 += __shfl_xor(a1, off, 64);
        a2 += __shfl_xor(a2, off, 64);
        a3 += __shfl_xor(a3, off, 64);
    }
}

struct Params {
    const float *x_a, *x_hp;
    const float *W_ih_a, *W_hh_a, *b_ih_a, *b_hh_a;
    const float *W_out_a, *b_out_a, *W_sum, *b_sum;
    const float *W_ih_hp, *W_hh_hp, *b_ih_hp, *b_hh_hp, *W_out_hp, *b_out_hp;
    __half *hW_ih_a, *hW_hh_a, *hW_sum, *hW_ih_hp, *hW_hh_hp, *hW_out_a, *hW_out_hp;
    float *gates_a, *h_sum, *gacc, *h_a, *c_a0, *c_a1, *h_hp, *c_hp;
    float *logits_a, *logits_hp, *a_vec, *out;
};

// ===========================================================================
// kA: all big GEMVs, one wave per row, x-vector staged ONCE PER BLOCK in LDS
// (4 waves share it — 4x less x-traffic through L1/L2 than per-wave reads).
//   blocks [0,2048):    gates_a = W_ih_a·a + W_hh_a·h_a + b      (x: a|h_a, 9KB)
//   blocks [2048,2560): h_sum   = relu(W_sum·h_hp + b)           (x: h_hp, 16KB)
//   blocks [2560,6656): gacc    = W_hh_hp·c_hp + b               (x: c_hp, 16KB)
//   blocks [6656,6720): logits_hp(t-1) = W_out_hp·h_hp + b       (t>=1)
// t==0 reads fp32 sources (exact init: a=1/256, h=x, c=0) while writing the
// fp16 copies used at t>=1; t==1 same for W_out_hp.
// ===========================================================================
__global__ __launch_bounds__(256) void kA(Params p, int t)
{
    __shared__ __align__(16) float xs[4096];   // 16 KB
    const int tid = threadIdx.x, lane = tid & 63, wv = tid >> 6;
    const int blk = blockIdx.x;

    if (blk < 2048) {
        // ---- gates_a rows; xs[0..255]=a, xs[256..2303]=h_a ----
        if (t == 0) {
            xs[tid] = 1.0f / 256.0f;
            for (int i = tid; i < H_A; i += 256) xs[256 + i] = p.x_a[i];
        } else {
            xs[tid] = p.a_vec[tid];
            for (int i = tid; i < H_A; i += 256) xs[256 + i] = p.h_a[i];
        }
        __syncthreads();
        const int r = (blk << 2) | wv;
        const float4* xa4 = (const float4*)xs;
        const float4* xh4 = (const float4*)(xs + 256);
        float acc;
        if (t == 0) {
            float4 wf = ((const float4*)(p.W_ih_a + (size_t)r * 256))[lane];
            ((Half4*)(p.hW_ih_a + (size_t)r * 256))[lane] = cvt4_(wf);
            acc = dot4_(wf, xa4[lane]);
            const float4* whf = (const float4*)(p.W_hh_a + (size_t)r * H_A);
            Half8* dsth = (Half8*)(p.hW_hh_a + (size_t)r * H_A);
#pragma unroll
            for (int it = 0; it < 4; ++it) {
                int idx = it * 64 + lane;
                float4 w0 = whf[2 * idx], w1 = whf[2 * idx + 1];
                dsth[idx] = cvt8_(w0, w1);
                acc += dot4_(w0, xh4[2 * idx]) + dot4_(w1, xh4[2 * idx + 1]);
            }
        } else {
            Half4 w = ((const Half4*)(p.hW_ih_a + (size_t)r * 256))[lane];
            float4 x = xa4[lane];
            float2 w0 = __half22float2(w.a), w1 = __half22float2(w.b);
            acc = w0.x * x.x + w0.y * x.y + w1.x * x.z + w1.y * x.w;
            const Half8* wh = (const Half8*)(p.hW_hh_a + (size_t)r * H_A);
#pragma unroll
            for (int it = 0; it < 4; ++it) {
                int idx = it * 64 + lane;
                acc += dot8h_(wh[idx], xh4[2 * idx], xh4[2 * idx + 1]);
            }
        }
        acc = waveReduceSum(acc);
        if (lane == 0) p.gates_a[r] = acc + p.b_ih_a[r] + p.b_hh_a[r];
    } else if (blk < 2560) {
        // ---- h_sum rows; xs = h_hp (x_hp at t0) ----
        const int rr = ((blk - 2048) << 2) | wv;
        const float* src = (t == 0) ? p.x_hp : p.h_hp;
        for (int i = tid; i < H_HP; i += 256) xs[i] = src[i];
        __syncthreads();
        const float4* x4 = (const float4*)xs;
        float acc = 0.0f;
        if (t == 0) {
            const float4* wf = (const float4*)(p.W_sum + (size_t)rr * H_HP);
            Half8* dsth = (Half8*)(p.hW_sum + (size_t)rr * H_HP);
#pragma unroll
            for (int it = 0; it < 8; ++it) {
                int idx = it * 64 + lane;
                float4 w0 = wf[2 * idx], w1 = wf[2 * idx + 1];
                dsth[idx] = cvt8_(w0, w1);
                acc += dot4_(w0, x4[2 * idx]) + dot4_(w1, x4[2 * idx + 1]);
            }
        } else {
            const Half8* ww = (const Half8*)(p.hW_sum + (size_t)rr * H_HP);
#pragma unroll
            for (int it = 0; it < 8; ++it) {
                int idx = it * 64 + lane;
                acc += dot8h_(ww[idx], x4[2 * idx], x4[2 * idx + 1]);
            }
        }
        acc = waveReduceSum(acc);
        if (lane == 0) p.h_sum[rr] = fmaxf(acc + p.b_sum[rr], 0.0f);
    } else if (blk < 6656) {
        // ---- gacc rows; xs = c_hp; t0: convert-only (c_hp(-1)=0 exact) ----
        const int rg = ((blk - 2560) << 2) | wv;
        if (t == 0) {
            const float4* wf = (const float4*)(p.W_hh_hp + (size_t)rg * H_HP);
            Half8* dsth = (Half8*)(p.hW_hh_hp + (size_t)rg * H_HP);
#pragma unroll
            for (int it = 0; it < 8; ++it) {
                int idx = it * 64 + lane;
                dsth[idx] = cvt8_(wf[2 * idx], wf[2 * idx + 1]);
            }
            if (lane == 0) p.gacc[rg] = p.b_ih_hp[rg] + p.b_hh_hp[rg];
        } else {
            for (int i = tid; i < H_HP; i += 256) xs[i] = p.c_hp[i];
            __syncthreads();
            const float4* x4 = (const float4*)xs;
            const Half8* ww = (const Half8*)(p.hW_hh_hp + (size_t)rg * H_HP);
            float acc = 0.0f;
#pragma unroll
            for (int it = 0; it < 8; ++it) {
                int idx = it * 64 + lane;
                acc += dot8h_(ww[idx], x4[2 * idx], x4[2 * idx + 1]);
            }
            acc = waveReduceSum(acc);
            if (lane == 0) p.gacc[rg] = acc + p.b_ih_hp[rg] + p.b_hh_hp[rg];
        }
    } else {
        // ---- logits_hp(t-1) rows; xs = h_hp(t-1); t>=1 only ----
        if (t == 0) return;
        const int ro = ((blk - 6656) << 2) | wv;
        for (int i = tid; i < H_HP; i += 256) xs[i] = p.h_hp[i];
        __syncthreads();
        const float4* x4 = (const float4*)xs;
        float acc = 0.0f;
        if (t == 1) {
            const float4* wf = (const float4*)(p.W_out_hp + (size_t)ro * H_HP);
            Half8* dsth = (Half8*)(p.hW_out_hp + (size_t)ro * H_HP);
#pragma unroll
            for (int it = 0; it < 8; ++it) {
                int idx = it * 64 + lane;
                float4 w0 = wf[2 * idx], w1 = wf[2 * idx + 1];
                dsth[idx] = cvt8_(w0, w1);
                acc += dot4_(w0, x4[2 * idx]) + dot4_(w1, x4[2 * idx + 1]);
            }
        } else {
            const Half8* ww = (const Half8*)(p.hW_out_hp + (size_t)ro * H_HP);
#pragma unroll
            for (int it = 0; it < 8; ++it) {
                int idx = it * 64 + lane;
                acc += dot8h_(ww[idx], x4[2 * idx], x4[2 * idx + 1]);
            }
        }
        acc = waveReduceSum(acc);
        if (lane == 0) p.logits_hp[ro] = acc + p.b_out_hp[ro];
    }
}

// ===========================================================================
// kB: arch pointwise LSTM (redundant per block, h into LDS) + W_out_a GEMV.
// 64 blocks x 256 threads -> 256 rows (one per wave). Block 0 writes state.
// t==0: c_a = 0 exactly; converts W_out_a to fp16 while computing from fp32.
// ===========================================================================
__global__ __launch_bounds__(256) void kB(Params p, int t)
{
    __shared__ __align__(16) float h_s[H_A];
    const int tid = threadIdx.x;
    const float* cin = (t & 1) ? p.c_a1 : p.c_a0;
    float* cout = (t & 1) ? p.c_a0 : p.c_a1;
#pragma unroll
    for (int k = 0; k < 8; ++k) {
        int e = tid + k * 256;
        float gi = p.gates_a[e], gf = p.gates_a[H_A + e];
        float gg = p.gates_a[2 * H_A + e], go = p.gates_a[3 * H_A + e];
        float ci = (t == 0) ? 0.0f : cin[e];
        float c = fsig_(gf) * ci + fsig_(gi) * ftanh_(gg);
        float h = fsig_(go) * ftanh_(c);
        h_s[e] = h;
        if (blockIdx.x == 0) { cout[e] = c; p.h_a[e] = h; }
    }
    __syncthreads();
    const int lane = tid & 63;
    const int r = (blockIdx.x << 2) | (tid >> 6);
    const float4* h4 = (const float4*)h_s;
    float acc = 0.0f;
    if (t == 0) {
        const float4* wf = (const float4*)(p.W_out_a + (size_t)r * H_A);
        Half8* dsth = (Half8*)(p.hW_out_a + (size_t)r * H_A);
#pragma unroll
        for (int it = 0; it < 4; ++it) {
            int idx = it * 64 + lane;
            float4 w0 = wf[2 * idx], w1 = wf[2 * idx + 1];
            dsth[idx] = cvt8_(w0, w1);
            acc += dot4_(w0, h4[2 * idx]) + dot4_(w1, h4[2 * idx + 1]);
        }
    } else {
        const Half8* ww = (const Half8*)(p.hW_out_a + (size_t)r * H_A);
#pragma unroll
        for (int it = 0; it < 4; ++it) {
            int idx = it * 64 + lane;
            acc += dot8h_(ww[idx], h4[2 * idx], h4[2 * idx + 1]);
        }
    }
    acc = waveReduceSum(acc);
    if (lane == 0) p.logits_a[r] = acc + p.b_out_a[r];
}

// ===========================================================================
// kC: block-redundant dual softmax (a(t) from logits_a; a_hp(t-1) from
// logits_hp — t==0 uses logits 0 -> exactly 1/256) + W_ih_hp GEMV + hp
// pointwise LSTM (reference's swapped states: cell input = [h_a, h_sum]).
// 1024 blocks x 256 threads; wave w owns element e: rows e, 4096+e, 8192+e,
// 12288+e (i,f,g,o). Block 0 writes a_vec, out_a[t], out_hp[t-1].
// ===========================================================================
__global__ __launch_bounds__(256) void kC(Params p, int t)
{
    __shared__ __align__(16) float p_all[512];
    __shared__ float red[8];
    const int tid = threadIdx.x, lane = tid & 63, wv = tid >> 6;
    float la = p.logits_a[tid];
    float lh = (t == 0) ? 0.0f : p.logits_hp[tid];
    float ma = la, mh = lh;
#pragma unroll
    for (int off = 32; off > 0; off >>= 1) {
        ma = fmaxf(ma, __shfl_xor(ma, off, 64));
        mh = fmaxf(mh, __shfl_xor(mh, off, 64));
    }
    if (lane == 0) { red[wv] = ma; red[4 + wv] = mh; }
    __syncthreads();
    ma = fmaxf(fmaxf(red[0], red[1]), fmaxf(red[2], red[3]));
    mh = fmaxf(fmaxf(red[4], red[5]), fmaxf(red[6], red[7]));
    __syncthreads();
    float ea = __expf(la - ma), eh = __expf(lh - mh);
    float sa = waveReduceSum(ea), sh = waveReduceSum(eh);
    if (lane == 0) { red[wv] = sa; red[4 + wv] = sh; }
    __syncthreads();
    sa = red[0] + red[1] + red[2] + red[3];
    sh = red[4] + red[5] + red[6] + red[7];
    float pa = ea / sa, ph = eh / sh;
    p_all[tid] = pa;
    p_all[256 + tid] = ph;
    if (blockIdx.x == 0) {
        p.a_vec[tid] = pa;
        p.out[(size_t)t * 256 + tid] = pa;                          // out_a[t]
        if (t > 0) p.out[3072 + (size_t)(t - 1) * 256 + tid] = ph;  // out_hp[t-1]
    }
    __syncthreads();
    float4 xa = ((const float4*)p_all)[2 * lane];
    float4 xb = ((const float4*)p_all)[2 * lane + 1];
    const int e = (blockIdx.x << 2) | wv;   // 0..4095
    float s0, s1, s2, s3;
    if (t == 0) {
        auto rowdot_cvt = [&](int r) -> float {
            const float4* wf = (const float4*)(p.W_ih_hp + (size_t)r * 512);
            float4 u = wf[2 * lane], v = wf[2 * lane + 1];
            ((Half8*)(p.hW_ih_hp + (size_t)r * 512))[lane] = cvt8_(u, v);
            return dot4_(u, xa) + dot4_(v, xb);
        };
        s0 = rowdot_cvt(e);
        s1 = rowdot_cvt(4096 + e);
        s2 = rowdot_cvt(8192 + e);
        s3 = rowdot_cvt(12288 + e);
    } else {
        Half8 w0 = ((const Half8*)(p.hW_ih_hp + (size_t)e * 512))[lane];
        Half8 w1 = ((const Half8*)(p.hW_ih_hp + (size_t)(4096 + e) * 512))[lane];
        Half8 w2 = ((const Half8*)(p.hW_ih_hp + (size_t)(8192 + e) * 512))[lane];
        Half8 w3 = ((const Half8*)(p.hW_ih_hp + (size_t)(12288 + e) * 512))[lane];
        s0 = dot8h_(w0, xa, xb);
        s1 = dot8h_(w1, xa, xb);
        s2 = dot8h_(w2, xa, xb);
        s3 = dot8h_(w3, xa, xb);
    }
    waveReduce4(s0, s1, s2, s3);
    if (lane == 0) {
        float gi = s0 + p.gacc[e];
        float gf = s1 + p.gacc[4096 + e];
        float gg = s2 + p.gacc[8192 + e];
        float go = s3 + p.gacc[12288 + e];
        float prev = (e < H_A) ? p.h_a[e] : p.h_sum[e - H_A];
        float c = fsig_(gf) * prev + fsig_(gi) * ftanh_(gg);
        float h = fsig_(go) * ftanh_(c);
        p.c_hp[e] = c;
        p.h_hp[e] = h;
    }
}

// ===========================================================================
// tail: logits_hp(11) = W_out_hp·h_hp(11) (64 blocks), then softmax (1 block)
// ===========================================================================
__global__ __launch_bounds__(256) void kTail_gemv(Params p)
{
    __shared__ __align__(16) float xs[H_HP];
    const int tid = threadIdx.x, lane = tid & 63;
    for (int i = tid; i < H_HP; i += 256) xs[i] = p.h_hp[i];
    __syncthreads();
    const int r = (blockIdx.x << 2) | (tid >> 6);
    const Half8* ww = (const Half8*)(p.hW_out_hp + (size_t)r * H_HP);
    const float4* x4 = (const float4*)xs;
    float acc = 0.0f;
#pragma unroll
    for (int it = 0; it < 8; ++it) {
        int idx = it * 64 + lane;
        acc += dot8h_(ww[idx], x4[2 * idx], x4[2 * idx + 1]);
    }
    acc = waveReduceSum(acc);
    if (lane == 0) p.logits_hp[r] = acc + p.b_out_hp[r];
}

__global__ __launch_bounds__(256) void kTail_softmax(Params p)
{
    __shared__ float red[4];
    const int tid = threadIdx.x, lane = tid & 63, wv = tid >> 6;
    float v = p.logits_hp[tid];
    float m = v;
#pragma unroll
    for (int off = 32; off > 0; off >>= 1) m = fmaxf(m, __shfl_xor(m, off, 64));
    if (lane == 0) red[wv] = m;
    __syncthreads();
    m = fmaxf(fmaxf(red[0], red[1]), fmaxf(red[2], red[3]));
    __syncthreads();
    float e = __expf(v - m);
    float s = waveReduceSum(e);
    if (lane == 0) red[wv] = s;
    __syncthreads();
    s = red[0] + red[1] + red[2] + red[3];
    p.out[3072 + 11 * 256 + tid] = e / s;
}

// ---------------------------------------------------------------------------

extern "C" void kernel_launch(void* const* d_in, const int* in_sizes, int n_in,
                              void* d_out, int out_size, void* d_ws, size_t ws_size,
                              hipStream_t stream)
{
    Params p;
    p.x_a      = (const float*)d_in[0];
    p.x_hp     = (const float*)d_in[1];
    p.W_ih_a   = (const float*)d_in[2];
    p.W_hh_a   = (const float*)d_in[3];
    p.b_ih_a   = (const float*)d_in[4];
    p.b_hh_a   = (const float*)d_in[5];
    p.W_out_a  = (const float*)d_in[6];
    p.b_out_a  = (const float*)d_in[7];
    p.W_sum    = (const float*)d_in[8];
    p.b_sum    = (const float*)d_in[9];
    p.W_ih_hp  = (const float*)d_in[10];
    p.W_hh_hp  = (const float*)d_in[11];
    p.b_ih_hp  = (const float*)d_in[12];
    p.b_hh_hp  = (const float*)d_in[13];
    p.W_out_hp = (const float*)d_in[14];
    p.b_out_hp = (const float*)d_in[15];

    // ws layout: fp16 weights first (16B aligned), then fp32 state
    p.hW_ih_a   = (__half*)d_ws;                     //  2,097,152 halves
    p.hW_hh_a   = p.hW_ih_a   + 2097152;             // 16,777,216
    p.hW_sum    = p.hW_hh_a   + 16777216;            //  8,388,608
    p.hW_ih_hp  = p.hW_sum    + 8388608;             //  8,388,608
    p.hW_hh_hp  = p.hW_ih_hp  + 8388608;             // 67,108,864
    p.hW_out_a  = p.hW_hh_hp  + 67108864;            //    524,288
    p.hW_out_hp = p.hW_out_a  + 524288;              //  1,048,576
    float* ws = (float*)(p.hW_out_hp + 1048576);

    p.gates_a   = ws;           // 8192
    p.h_sum     = ws + 8192;    // 2048
    p.gacc      = ws + 10240;   // 16384
    p.h_a       = ws + 26624;   // 2048
    p.c_a0      = ws + 28672;   // 2048
    p.c_a1      = ws + 30720;   // 2048
    p.h_hp      = ws + 32768;   // 4096
    p.c_hp      = ws + 36864;   // 4096
    p.logits_a  = ws + 40960;   // 256
    p.logits_hp = ws + 41216;   // 256
    p.a_vec     = ws + 41472;   // 256
    p.out       = (float*)d_out;

    for (int t = 0; t < DEPTH; ++t) {
        kA<<<6720, 256, 0, stream>>>(p, t);
        kB<<<64, 256, 0, stream>>>(p, t);
        kC<<<1024, 256, 0, stream>>>(p, t);
    }
    kTail_gemv<<<64, 256, 0, stream>>>(p);
    kTail_softmax<<<1, 256, 0, stream>>>(p);
}